// Round 16
// baseline (49.208 us; speedup 1.0000x reference)
//
#include <hip/hip_runtime.h>
#include <math.h>

// LNCC via commuted separable order W -> D -> H (box filters commute), as
// 3 streaming kernels (no LDS, no barriers — every LDS/fused/hinted variant
// measured worse: R12 LDS-fusion 25-35% BW, R14 fused-finalize 32-VGPR
// collapse, R5/R6 min-waves hints spill):
//  K1 lncc_wd: W+D fused. Thread owns (b, h, w-quad, d-chunk of 4). For each
//     visited slice: 3x float4 loads per array, pm-permute for w-reflect,
//     5-ch sliding W-sums, quantize x(65535/9) -> u16. Integer running
//     D-window sums S[5][4]; leaving-edge W-sums are RECOMPUTED (deterministic
//     -> bit-identical, no 90-reg FIFO). Emit round(S/9) as u16 wdq (40 MB).
//     Traffic 72 MB vs 152 MB for the split W,H pair.
//  K2 lncc_hl: H+LNCC fused — exactly the proven K3 structure with h instead
//     of d (contiguous rows instead of SLICE stride): integer-exact sliding,
//     LNCC with DQ3, block reduce.
//  K3 final: deterministic double reduction -> d_out[0] = -mean.
// Quantization chain (same error budget as the passing R11 chain):
//   Wq = round(Wsum*65535/9); wdq = round(sum9(Wq)/9) ~= WD*65535/81;
//   H-sum = sum9(wdq) < 2^24 exact; E[.] = S*81/65535/729 = DQ3.

#define NVOX 4194304        // 2*128*128*128
#define SLICE 16384         // 128*128
#define S1 (65535.0f / 9.0f)
#define DQ3 ((float)(81.0 / 65535.0 / 729.0))

__device__ __forceinline__ int refl(int p) {
    // reflect (no edge repeat) for dim 128
    return 127 - abs(abs(p) - 127);
}

// Visit slice `s`: compute the 5-channel quantized W-sums for this thread's
// 4 w-columns and accumulate wgt*(them) into S. Deterministic: recomputation
// yields bit-identical values.
__device__ __forceinline__ void wd_visit(const float* __restrict__ fb,
                                         const float* __restrict__ wb,
                                         int s, int edge, int wgt,
                                         unsigned int S[5][4]) {
    const float* fr = fb + (size_t)s * SLICE;
    const float* wr = wb + (size_t)s * SLICE;
    float Lf[12], Lw[12];
    *(float4*)&Lf[0] = *(const float4*)&fr[0];
    *(float4*)&Lf[4] = *(const float4*)&fr[4];
    *(float4*)&Lf[8] = *(const float4*)&fr[8];
    *(float4*)&Lw[0] = *(const float4*)&wr[0];
    *(float4*)&Lw[4] = *(const float4*)&wr[4];
    *(float4*)&Lw[8] = *(const float4*)&wr[8];

    // window cols w0-4 .. w0+7 (12 wide for 4 outputs), reflected at w edges
    float fv[12], wv[12];
    if (edge == 1) {          // w0==0: cols -4..7 -> {4,3,2,1,0,1,2,3,4,5,6,7}
        const int pm[12] = {4,3,2,1,0,1,2,3,4,5,6,7};
#pragma unroll
        for (int t = 0; t < 12; ++t) { fv[t] = Lf[pm[t]]; wv[t] = Lw[pm[t]]; }
    } else if (edge == 2) {   // w0==124 (jbc=116): cols 120..131
        const int pm[12] = {4,5,6,7,8,9,10,11,10,9,8,7};
#pragma unroll
        for (int t = 0; t < 12; ++t) { fv[t] = Lf[pm[t]]; wv[t] = Lw[pm[t]]; }
    } else {
#pragma unroll
        for (int t = 0; t < 12; ++t) { fv[t] = Lf[t]; wv[t] = Lw[t]; }
    }

    float sf = 0.f, sw = 0.f, sff = 0.f, sww = 0.f, sfw = 0.f;
#pragma unroll
    for (int t = 0; t < 9; ++t) {
        sf += fv[t]; sw += wv[t];
        sff = fmaf(fv[t], fv[t], sff);
        sww = fmaf(wv[t], wv[t], sww);
        sfw = fmaf(fv[t], wv[t], sfw);
    }
    S[0][0] += wgt * (unsigned int)(unsigned short)fmaf(sf,  S1, 0.5f);
    S[1][0] += wgt * (unsigned int)(unsigned short)fmaf(sw,  S1, 0.5f);
    S[2][0] += wgt * (unsigned int)(unsigned short)fmaf(sff, S1, 0.5f);
    S[3][0] += wgt * (unsigned int)(unsigned short)fmaf(sww, S1, 0.5f);
    S[4][0] += wgt * (unsigned int)(unsigned short)fmaf(sfw, S1, 0.5f);
#pragma unroll
    for (int k = 1; k < 4; ++k) {
        float fe = fv[k + 8], fx = fv[k - 1];
        float we = wv[k + 8], wx = wv[k - 1];
        sf += fe - fx; sw += we - wx;
        sff = fmaf(fe, fe, sff); sff = fmaf(-fx, fx, sff);
        sww = fmaf(we, we, sww); sww = fmaf(-wx, wx, sww);
        sfw = fmaf(fe, we, sfw); sfw = fmaf(-fx, wx, sfw);
        S[0][k] += wgt * (unsigned int)(unsigned short)fmaf(sf,  S1, 0.5f);
        S[1][k] += wgt * (unsigned int)(unsigned short)fmaf(sw,  S1, 0.5f);
        S[2][k] += wgt * (unsigned int)(unsigned short)fmaf(sff, S1, 0.5f);
        S[3][k] += wgt * (unsigned int)(unsigned short)fmaf(sww, S1, 0.5f);
        S[4][k] += wgt * (unsigned int)(unsigned short)fmaf(sfw, S1, 0.5f);
    }
}

__global__ __launch_bounds__(256)
void lncc_wd_kernel(const float* __restrict__ f, const float* __restrict__ w,
                    unsigned short* __restrict__ wdq) {
    // 262144 threads (1024 blocks): thread -> (b, d-chunk(32), h, w-quad)
    const int gtid = blockIdx.x * 256 + threadIdx.x;
    const int wq4 = gtid & 31;           // w0 = 4*wq4
    const int h   = (gtid >> 5) & 127;
    const int dc  = (gtid >> 12) & 31;   // chunk of 4 d's
    const int b   = gtid >> 17;
    const int w0  = wq4 << 2;
    const int d0  = dc << 2;

    const int edge = (wq4 == 0) ? 1 : ((wq4 == 31) ? 2 : 0);
    const int jbc  = (edge == 1) ? 0 : ((edge == 2) ? 116 : (w0 - 4));

    const float* fb = f + (size_t)b * (128 * SLICE) + h * 128 + jbc;
    const float* wb = w + (size_t)b * (128 * SLICE) + h * 128 + jbc;

    unsigned int S[5][4];
#pragma unroll
    for (int c = 0; c < 5; ++c)
#pragma unroll
        for (int k = 0; k < 4; ++k) S[c][k] = 0u;

    // prologue: the 9 window slices of output d0 (refl makes duplicates,
    // which are simply recomputed — weight handled naturally)
#pragma unroll
    for (int i = 0; i < 9; ++i)
        wd_visit(fb, wb, refl(d0 - 4 + i), edge, 1u, S);

#pragma unroll
    for (int k = 0; k < 4; ++k) {
        const int d = d0 + k;
        // emit: wdq = round(S/9), 5 ch x 4 w packed as uint2
#pragma unroll
        for (int c = 0; c < 5; ++c) {
            unsigned int q0 = (unsigned short)fmaf((float)S[c][0], 1.0f / 9.0f, 0.5f);
            unsigned int q1 = (unsigned short)fmaf((float)S[c][1], 1.0f / 9.0f, 0.5f);
            unsigned int q2 = (unsigned short)fmaf((float)S[c][2], 1.0f / 9.0f, 0.5f);
            unsigned int q3 = (unsigned short)fmaf((float)S[c][3], 1.0f / 9.0f, 0.5f);
            uint2 Q; Q.x = q0 | (q1 << 16); Q.y = q2 | (q3 << 16);
            *(uint2*)&wdq[(size_t)c * NVOX + (size_t)(b * 128 + d) * SLICE
                          + (size_t)h * 128 + w0] = Q;
        }
        if (k < 3) {   // slide window d -> d+1: add refl(d+5), remove refl(d-4)
            wd_visit(fb, wb, refl(d + 5), edge,  1u, S);
            wd_visit(fb, wb, refl(d - 4), edge, (unsigned int)-1, S);
        }
    }
}

__global__ __launch_bounds__(256)
void lncc_hl_kernel(const unsigned short* __restrict__ wdq,
                    float* __restrict__ partials) {
    // 524288 threads (2048 blocks): thread -> (bd, h-chunk(16), w), 8 h-outputs
    const int gtid = blockIdx.x * 256 + threadIdx.x;
    const int wc = gtid & 127;
    const int hc = (gtid >> 7) & 15;
    const int bd = gtid >> 11;           // b*128 + d, 0..255
    const int h0 = hc << 3;

    float s[5][8];
#pragma unroll
    for (int c = 0; c < 5; ++c) {
        const unsigned short* bc = wdq + (size_t)c * NVOX + (size_t)bd * SLICE + wc;
        float v[16];
#pragma unroll
        for (int t = 0; t < 16; ++t) {
            int hh = refl(h0 - 4 + t);
            v[t] = (float)bc[(size_t)hh * 128];
        }
        float acc = 0.f;
#pragma unroll
        for (int t = 0; t < 9; ++t) acc += v[t];
        s[c][0] = acc;
#pragma unroll
        for (int j = 1; j < 8; ++j) {
            acc += v[j + 8] - v[j - 1];
            s[c][j] = acc;
        }
    }

    float lsum = 0.f;
#pragma unroll
    for (int j = 0; j < 8; ++j) {
        float mf = s[0][j] * DQ3;
        float mw = s[1][j] * DQ3;
        float sgf = fmaxf(s[2][j] * DQ3 - mf * mf, 1e-8f);
        float sgw = fmaxf(s[3][j] * DQ3 - mw * mw, 1e-8f);
        float sfw = s[4][j] * DQ3 - mf * mw;
        float denom = fmaxf(sqrtf(fmaxf(sgf * sgw, 1e-16f)), 1e-8f);
        float l = sfw / denom;
        lsum += fminf(fmaxf(l, -10.f), 10.f);
    }

#pragma unroll
    for (int off = 32; off > 0; off >>= 1)
        lsum += __shfl_down(lsum, off, 64);
    __shared__ float red[4];
    int lane = threadIdx.x & 63, wid = threadIdx.x >> 6;
    if (lane == 0) red[wid] = lsum;
    __syncthreads();
    if (threadIdx.x == 0)
        partials[blockIdx.x] = red[0] + red[1] + red[2] + red[3];
}

__global__ __launch_bounds__(256)
void lncc_final_kernel(const float* __restrict__ partials, int n,
                       float* __restrict__ out) {
    __shared__ double rd[256];
    double acc = 0.0;
    for (int i = threadIdx.x; i < n; i += 256) acc += (double)partials[i];
    rd[threadIdx.x] = acc;
    __syncthreads();
    for (int s = 128; s > 0; s >>= 1) {
        if (threadIdx.x < s) rd[threadIdx.x] += rd[threadIdx.x + s];
        __syncthreads();
    }
    if (threadIdx.x == 0) out[0] = (float)(-rd[0] / (double)NVOX);
}

extern "C" void kernel_launch(void* const* d_in, const int* in_sizes, int n_in,
                              void* d_out, int out_size, void* d_ws, size_t ws_size,
                              hipStream_t stream) {
    const float* f = (const float*)d_in[0];
    const float* w = (const float*)d_in[1];
    float* out = (float*)d_out;

    unsigned short* wdq = (unsigned short*)d_ws;                    // 40 MB
    float* partials = (float*)((char*)d_ws + (size_t)10 * NVOX);    // 2048 f

    lncc_wd_kernel<<<1024, 256, 0, stream>>>(f, w, wdq);
    lncc_hl_kernel<<<2048, 256, 0, stream>>>(wdq, partials);
    lncc_final_kernel<<<1, 256, 0, stream>>>(partials, 2048, out);
}